// Round 1
// baseline (13480.156 us; speedup 1.0000x reference)
//
#include <hip/hip_runtime.h>
#include <math.h>

#define SEQ 512
#define BB 64      // batch
#define IN_DIM 128
#define HH 256     // hidden
#define NL 6       // layers
#define G3 (3*HH)  // 768

// workspace layout (floats):
//   h_state[NL][BB][HH]            at offset 0            (98304 floats)
//   ring[NL-1][2][BB][HH]          at offset RING_OFF     (163840 floats)
#define H_STATE_OFF 0
#define RING_OFF (NL*BB*HH)

// One wave-step: layer l processes t = s - l. Grid: (HH/8 j-blocks, BB/16 b-blocks, NL layers).
// 128 threads: thread owns (b = tid&15, j = j0 + (tid>>4)). Computes all 3 gates for its j.
__global__ __launch_bounds__(128) void gru_step_kernel(
    const float* __restrict__ x,
    const float* __restrict__ w_ih0,
    const float* __restrict__ w_ih_rest,
    const float* __restrict__ w_hh,
    const float* __restrict__ b_ih,
    const float* __restrict__ b_hh,
    float* __restrict__ ws,
    float* __restrict__ out_y,
    int s)
{
    const int l = blockIdx.z;
    const int t = s - l;
    if (t < 0 || t >= SEQ) return;

    const int b0 = blockIdx.y * 16;
    const int j0 = blockIdx.x * 8;
    const int tid = threadIdx.x;
    const int K_in = (l == 0) ? IN_DIM : HH;
    const int SI = K_in + 4;            // padded LDS stride (float4-aligned, bank-spread)
    const int SH = HH + 4;

    __shared__ float lds_in[16 * (HH + 4)];
    __shared__ float lds_h[16 * (HH + 4)];

    float* h_state = ws + H_STATE_OFF + (size_t)l * BB * HH;

    const float* in_src;
    if (l == 0) in_src = x + (size_t)t * BB * IN_DIM + (size_t)b0 * IN_DIM;
    else        in_src = ws + RING_OFF + ((size_t)((l - 1) * 2 + (t & 1))) * BB * HH + (size_t)b0 * HH;

    // stage input rows [16][K_in] into LDS
    const int nchunk_in = 16 * (K_in / 4);
    for (int c = tid; c < nchunk_in; c += 128) {
        int bb = c / (K_in / 4);
        int kk = (c % (K_in / 4)) * 4;
        float4 v = *(const float4*)(in_src + (size_t)bb * K_in + kk);
        *(float4*)(&lds_in[bb * SI + kk]) = v;
    }
    // stage h rows [16][HH] into LDS
    const float* h_src = h_state + (size_t)b0 * HH;
    const int nchunk_h = 16 * (HH / 4);
    for (int c = tid; c < nchunk_h; c += 128) {
        int bb = c / (HH / 4);
        int kk = (c % (HH / 4)) * 4;
        float4 v = *(const float4*)(h_src + (size_t)bb * HH + kk);
        *(float4*)(&lds_h[bb * SH + kk]) = v;
    }
    __syncthreads();

    const int b = tid & 15;
    const int jj = tid >> 4;
    const int j = j0 + jj;

    const float* w_ih_l = (l == 0) ? w_ih0 : (w_ih_rest + (size_t)(l - 1) * G3 * HH);
    const float* w_hh_l = w_hh + (size_t)l * G3 * HH;

    // input-side dots (rows j, HH+j, 2*HH+j of w_ih_l)
    const float4* wir = (const float4*)(w_ih_l + (size_t)j * K_in);
    const float4* wiz = (const float4*)(w_ih_l + (size_t)(HH + j) * K_in);
    const float4* win = (const float4*)(w_ih_l + (size_t)(2 * HH + j) * K_in);
    const float* inrow = &lds_in[b * SI];

    float ar = 0.f, az = 0.f, an = 0.f;
    #pragma unroll 8
    for (int k4 = 0; k4 < K_in / 4; ++k4) {
        float4 xi = *(const float4*)(&inrow[4 * k4]);
        float4 a = wir[k4];
        float4 c = wiz[k4];
        float4 d = win[k4];
        ar += xi.x * a.x + xi.y * a.y + xi.z * a.z + xi.w * a.w;
        az += xi.x * c.x + xi.y * c.y + xi.z * c.z + xi.w * c.w;
        an += xi.x * d.x + xi.y * d.y + xi.z * d.z + xi.w * d.w;
    }

    // h-side dots (rows j, HH+j, 2*HH+j of w_hh_l)
    const float4* whr = (const float4*)(w_hh_l + (size_t)j * HH);
    const float4* whz = (const float4*)(w_hh_l + (size_t)(HH + j) * HH);
    const float4* whn = (const float4*)(w_hh_l + (size_t)(2 * HH + j) * HH);
    const float* hrow = &lds_h[b * SH];

    float hr = 0.f, hz = 0.f, hn = 0.f;
    #pragma unroll 8
    for (int k4 = 0; k4 < HH / 4; ++k4) {
        float4 xh = *(const float4*)(&hrow[4 * k4]);
        float4 a = whr[k4];
        float4 c = whz[k4];
        float4 d = whn[k4];
        hr += xh.x * a.x + xh.y * a.y + xh.z * a.z + xh.w * a.w;
        hz += xh.x * c.x + xh.y * c.y + xh.z * c.z + xh.w * c.w;
        hn += xh.x * d.x + xh.y * d.y + xh.z * d.z + xh.w * d.w;
    }

    const float bir = b_ih[l * G3 + j];
    const float biz = b_ih[l * G3 + HH + j];
    const float bin_ = b_ih[l * G3 + 2 * HH + j];
    const float bhr = b_hh[l * G3 + j];
    const float bhz = b_hh[l * G3 + HH + j];
    const float bhn = b_hh[l * G3 + 2 * HH + j];

    float r = 1.f / (1.f + expf(-(ar + bir + hr + bhr)));
    float z = 1.f / (1.f + expf(-(az + biz + hz + bhz)));
    float n = tanhf(an + bin_ + r * (hn + bhn));
    float h_old = hrow[j];
    float h_new = (1.f - z) * n + z * h_old;

    h_state[(size_t)(b0 + b) * HH + j] = h_new;
    if (l == NL - 1) {
        out_y[(size_t)t * BB * HH + (size_t)(b0 + b) * HH + j] = h_new;
    } else {
        ws[RING_OFF + ((size_t)(l * 2 + (t & 1))) * BB * HH + (size_t)(b0 + b) * HH + j] = h_new;
    }
}

extern "C" void kernel_launch(void* const* d_in, const int* in_sizes, int n_in,
                              void* d_out, int out_size, void* d_ws, size_t ws_size,
                              hipStream_t stream) {
    const float* x         = (const float*)d_in[0];
    const float* h0        = (const float*)d_in[1];
    const float* w_ih0     = (const float*)d_in[2];
    const float* w_ih_rest = (const float*)d_in[3];
    const float* w_hh      = (const float*)d_in[4];
    const float* b_ih      = (const float*)d_in[5];
    const float* b_hh      = (const float*)d_in[6];
    float* out = (float*)d_out;
    float* ws  = (float*)d_ws;

    // init h_state from h0
    hipMemcpyAsync(ws + H_STATE_OFF, h0, (size_t)NL * BB * HH * sizeof(float),
                   hipMemcpyDeviceToDevice, stream);

    dim3 grid(HH / 8, BB / 16, NL);
    for (int s = 0; s < SEQ + NL - 1; ++s) {
        gru_step_kernel<<<grid, 128, 0, stream>>>(x, w_ih0, w_ih_rest, w_hh,
                                                  b_ih, b_hh, ws, out, s);
    }

    // final hidden states -> tail of d_out
    hipMemcpyAsync(out + (size_t)SEQ * BB * HH, ws + H_STATE_OFF,
                   (size_t)NL * BB * HH * sizeof(float),
                   hipMemcpyDeviceToDevice, stream);
}

// Round 2
// 5262.756 us; speedup vs baseline: 2.5614x; 2.5614x over previous
//
#include <hip/hip_runtime.h>

#define SEQ 512
#define BB 64
#define IN_DIM 128
#define HH 256
#define NL 6
#define G3 768
#define KT 16            // K tiles of 32 -> K=512 (layer0 pads tail with zeros)
#define SA 520           // padded LDS stride in bf16 elems (1040 B, 16B-aligned)
#define CUS_PER_LAYER 16
#define JPC 16           // hidden units per CU
#define FLAG_STRIDE 16   // ints per flag (64 B line)

typedef short short8 __attribute__((ext_vector_type(8)));
typedef short short4v __attribute__((ext_vector_type(4)));
typedef float f32x4 __attribute__((ext_vector_type(4)));

#define RING_ELEMS (BB * HH)                       // bf16 elems per ring slot
#define RING_SHORTS (NL * 4 * RING_ELEMS)          // total ring shorts
#define FLAGS_OFF_BYTES (RING_SHORTS * 2)          // 786432
#define NFLAG_INTS (NL * (SEQ + 1) * FLAG_STRIDE)  // 49248 ints

__device__ __forceinline__ short f2bf(float f) {
    unsigned u = __builtin_bit_cast(unsigned, f);
    u += 0x7fffu + ((u >> 16) & 1u);   // RNE
    return (short)(u >> 16);
}
__device__ __forceinline__ float sigm(float v) {
    return __fdividef(1.f, 1.f + __expf(-v));
}
__device__ __forceinline__ float tanh_f(float v) {
    float e = __expf(2.f * v);
    return 1.f - __fdividef(2.f, e + 1.f);
}

__global__ __launch_bounds__(256, 1) void gru_persist(
    const float* __restrict__ x, const float* __restrict__ h0,
    const float* __restrict__ w_ih0, const float* __restrict__ w_ih_rest,
    const float* __restrict__ w_hh, const float* __restrict__ b_ih,
    const float* __restrict__ b_hh, float* __restrict__ y,
    short* __restrict__ ring, int* __restrict__ flags)
{
    const int bid = blockIdx.x;
    const int l = bid >> 4;               // layer
    const int jbase = (bid & 15) * JPC;   // this CU's hidden-unit base
    const int tid = threadIdx.x;
    const int lane = tid & 63;
    const int wave = tid >> 6;            // 4 waves: M-tile (16 batches each)
    const int q = lane >> 4;              // k-group / m-subrow group
    const int jj = lane & 15;
    const int jrow = jbase + jj;          // n-index (hidden unit)

    __shared__ short sAm[64 * SA];        // activations [b][k] bf16, 66560 B
    __shared__ float sH[64 * 17];         // fp32 h_old slice [b][jj], 4352 B
    __shared__ float sPad[2816];          // force 1 WG/CU (total >80 KB LDS)
    if (x == nullptr) sPad[0] = 1.f;      // never true; keeps allocation

    // ---- h0 init: fp32 copy to LDS + bf16 to ring slot 3 ((-1)&3) ----
    short* ring_init = ring + (l * 4 + 3) * RING_ELEMS;
    for (int i = tid; i < BB * JPC; i += 256) {
        int b = i >> 4, j2 = i & 15;
        float v = h0[(size_t)l * BB * HH + b * HH + jbase + j2];
        sH[b * 17 + j2] = v;
        ring_init[b * HH + jbase + j2] = f2bf(v);
    }
    __syncthreads();
    if (tid == 0) {
        __threadfence();
        atomicAdd(&flags[(l * (SEQ + 1) + 0) * FLAG_STRIDE], 1);
    }

    // zero layer-0 activation tail cols [384,512) once
    if (l == 0) {
        short8 z8 = {};
        for (int i = tid; i < 64 * 16; i += 256) {
            int row = i >> 4, c8 = (i & 15) * 8;
            *reinterpret_cast<short8*>(&sAm[row * SA + 384 + c8]) = z8;
        }
    }

    // ---- weight preload into registers (bf16 B-fragments) ----
    const int KIN = (l == 0) ? IN_DIM : HH;
    const float* wih = (l == 0) ? w_ih0 : (w_ih_rest + (size_t)(l - 1) * G3 * HH);
    const float* whh = w_hh + (size_t)l * G3 * HH;
    const int kq = q * 8;
    short8 Breg[3 * KT];
    #pragma unroll
    for (int g = 0; g < 3; ++g) {
        const int row = g * HH + jrow;
        #pragma unroll
        for (int kt = 0; kt < KT; ++kt) {
            int k = kt * 32 + kq;
            short8 v = {};
            const float* p = nullptr;
            if (k < KIN)            p = wih + (size_t)row * KIN + k;
            else if (k < KIN + HH)  p = whh + (size_t)row * HH + (k - KIN);
            if (p) {
                float4 a = *(const float4*)p;
                float4 c = *(const float4*)(p + 4);
                v[0] = f2bf(a.x); v[1] = f2bf(a.y); v[2] = f2bf(a.z); v[3] = f2bf(a.w);
                v[4] = f2bf(c.x); v[5] = f2bf(c.y); v[6] = f2bf(c.z); v[7] = f2bf(c.w);
            }
            Breg[g * KT + kt] = v;
        }
    }
    const float bsr = b_ih[l * G3 + jrow] + b_hh[l * G3 + jrow];
    const float bsz = b_ih[l * G3 + HH + jrow] + b_hh[l * G3 + HH + jrow];
    const float bin_ = b_ih[l * G3 + 2 * HH + jrow];
    const float bhn_ = b_hh[l * G3 + 2 * HH + jrow];

    const int ksplit = (l == 0) ? 4 : 8;       // x-side K-tiles
    const int Mbase = wave * 16;
    const int aoff = (Mbase + jj) * SA + kq;   // A-frag base (bf16 units)

    for (int t = 0; t < SEQ; ++t) {
        // ---- wait for dependencies (diagonal-ordered -> deadlock-free) ----
        if (tid == 0) {
            const int* f_own = &flags[(l * (SEQ + 1) + t) * FLAG_STRIDE];
            while (__hip_atomic_load(f_own, __ATOMIC_ACQUIRE, __HIP_MEMORY_SCOPE_AGENT) < CUS_PER_LAYER) {}
            if (l > 0) {
                const int* f_prev = &flags[((l - 1) * (SEQ + 1) + t + 1) * FLAG_STRIDE];
                while (__hip_atomic_load(f_prev, __ATOMIC_ACQUIRE, __HIP_MEMORY_SCOPE_AGENT) < CUS_PER_LAYER) {}
            }
            if (l < NL - 1 && t >= 4) {   // ring-slot reuse guard
                const int* f_next = &flags[((l + 1) * (SEQ + 1) + t - 3) * FLAG_STRIDE];
                while (__hip_atomic_load(f_next, __ATOMIC_ACQUIRE, __HIP_MEMORY_SCOPE_AGENT) < CUS_PER_LAYER) {}
            }
        }
        __syncthreads();

        // ---- stage activations into LDS [b][k] ----
        if (l == 0) {
            const float* xt = x + (size_t)t * BB * IN_DIM;
            #pragma unroll
            for (int i = 0; i < 8; ++i) {
                int c = tid + i * 256;
                int row = c >> 5, col = (c & 31) * 4;   // 32 float4-chunks per row
                float4 v = *(const float4*)(xt + row * IN_DIM + col);
                short4v s;
                s[0] = f2bf(v.x); s[1] = f2bf(v.y); s[2] = f2bf(v.z); s[3] = f2bf(v.w);
                *reinterpret_cast<short4v*>(&sAm[row * SA + col]) = s;
            }
            const short* hsrc = ring + (0 * 4 + ((t + 3) & 3)) * RING_ELEMS;
            #pragma unroll
            for (int i = 0; i < 8; ++i) {
                int c = tid + i * 256;
                int row = c >> 5, col = (c & 31) * 8;
                short8 v = *(const short8*)(hsrc + row * HH + col);
                *reinterpret_cast<short8*>(&sAm[row * SA + IN_DIM + col]) = v;
            }
        } else {
            const short* psrc = ring + ((l - 1) * 4 + (t & 3)) * RING_ELEMS;       // prev layer t
            const short* hsrc = ring + (l * 4 + ((t + 3) & 3)) * RING_ELEMS;       // own t-1
            #pragma unroll
            for (int i = 0; i < 8; ++i) {
                int c = tid + i * 256;
                int row = c >> 5, col = (c & 31) * 8;
                short8 v = *(const short8*)(psrc + row * HH + col);
                *reinterpret_cast<short8*>(&sAm[row * SA + col]) = v;
            }
            #pragma unroll
            for (int i = 0; i < 8; ++i) {
                int c = tid + i * 256;
                int row = c >> 5, col = (c & 31) * 8;
                short8 v = *(const short8*)(hsrc + row * HH + col);
                *reinterpret_cast<short8*>(&sAm[row * SA + HH + col]) = v;
            }
        }
        __syncthreads();

        // ---- MFMA: preact[b][gate rows], split x-side / h-side accumulators ----
        f32x4 ax0 = {}, ax1 = {}, ax2 = {}, ah0 = {}, ah1 = {}, ah2 = {};
        #pragma unroll
        for (int kt = 0; kt < KT; ++kt) {
            short8 a = *reinterpret_cast<const short8*>(&sAm[aoff + kt * 32]);
            if (kt < ksplit) {
                ax0 = __builtin_amdgcn_mfma_f32_16x16x32_bf16(a, Breg[0 * KT + kt], ax0, 0, 0, 0);
                ax1 = __builtin_amdgcn_mfma_f32_16x16x32_bf16(a, Breg[1 * KT + kt], ax1, 0, 0, 0);
                ax2 = __builtin_amdgcn_mfma_f32_16x16x32_bf16(a, Breg[2 * KT + kt], ax2, 0, 0, 0);
            } else {
                ah0 = __builtin_amdgcn_mfma_f32_16x16x32_bf16(a, Breg[0 * KT + kt], ah0, 0, 0, 0);
                ah1 = __builtin_amdgcn_mfma_f32_16x16x32_bf16(a, Breg[1 * KT + kt], ah1, 0, 0, 0);
                ah2 = __builtin_amdgcn_mfma_f32_16x16x32_bf16(a, Breg[2 * KT + kt], ah2, 0, 0, 0);
            }
        }

        // ---- gates (fp32) + writes ----
        short* rdst = ring + (l * 4 + (t & 3)) * RING_ELEMS;
        float* ydst = y + (size_t)t * BB * HH;
        #pragma unroll
        for (int r = 0; r < 4; ++r) {
            int b = Mbase + 4 * q + r;          // C/D: m = 4*(lane>>4)+reg
            float ho = sH[b * 17 + jj];
            float rg = sigm(ax0[r] + ah0[r] + bsr);
            float zg = sigm(ax1[r] + ah1[r] + bsz);
            float ng = tanh_f(ax2[r] + bin_ + rg * (ah2[r] + bhn_));
            float hn = ng + zg * (ho - ng);
            sH[b * 17 + jj] = hn;
            rdst[b * HH + jrow] = f2bf(hn);
            if (l == NL - 1) ydst[b * HH + jrow] = hn;
        }
        __syncthreads();
        if (tid == 0) {
            __threadfence();
            atomicAdd(&flags[(l * (SEQ + 1) + t + 1) * FLAG_STRIDE], 1);
        }
    }

    // ---- final hidden states (fp32 from LDS) ----
    for (int i = tid; i < BB * JPC; i += 256) {
        int b = i >> 4, j2 = i & 15;
        y[(size_t)SEQ * BB * HH + (size_t)l * BB * HH + b * HH + jbase + j2] = sH[b * 17 + j2];
    }
}

extern "C" void kernel_launch(void* const* d_in, const int* in_sizes, int n_in,
                              void* d_out, int out_size, void* d_ws, size_t ws_size,
                              hipStream_t stream) {
    (void)in_sizes; (void)n_in; (void)out_size; (void)ws_size;
    const float* x         = (const float*)d_in[0];
    const float* h0        = (const float*)d_in[1];
    const float* w_ih0     = (const float*)d_in[2];
    const float* w_ih_rest = (const float*)d_in[3];
    const float* w_hh      = (const float*)d_in[4];
    const float* b_ih      = (const float*)d_in[5];
    const float* b_hh      = (const float*)d_in[6];
    float* y = (float*)d_out;

    short* ring = (short*)d_ws;
    int* flags  = (int*)((char*)d_ws + FLAGS_OFF_BYTES);

    hipMemsetAsync(flags, 0, NFLAG_INTS * sizeof(int), stream);
    gru_persist<<<NL * CUS_PER_LAYER, 256, 0, stream>>>(
        x, h0, w_ih0, w_ih_rest, w_hh, b_ih, b_hh, y, ring, flags);
}